// Round 8
// baseline (492.529 us; speedup 1.0000x reference)
//
#include <hip/hip_runtime.h>

// CTC loss forward, T=1024, B=128, C=256, S=128, L=2S+1=257.
// R8: TWO batches per wave for in-wave ILP. Post-mortem of R1-R7: every
// memory arrangement (reg-resident/collapsed/atomic/LDS-DMA) = 115-135us,
// warm-L3 == cold, renorm-halving = null. The floor is in-order
// DEPENDENT-ISSUE serialization: ~35 mostly-chained VALU instrs/step at
// ~5-8cy operand latency each ~= 250cy/step, with 1 wave/SIMD and nothing
// to fill the gaps. More waves/SIMD can't shrink a wave's own step time;
// only intra-wave ILP can. So each wave now runs two independent 64-lane
// recursions (batches 2*blk, 2*blk+1) with fully-unrolled j=0,1 loops:
// two independent SSA chains at every point let the scheduler fill batch-0
// stalls with batch-1 issue. Plain HIP loads, depth-1 carried regs (R3
// proved the compiler pipelines this adequately), NO asm, NO walls.
// Differing input lengths: common floor(min/16) chunks unguarded, then a
// guarded tail with wave-uniform per-batch freeze (<=255 steps); renorm is
// exact so frozen batches renorm harmlessly (logC compensates).
//
// Kept verified pieces (absmax 0.0 across R3-R6): exp-domain FP64
// recursion, DPP wave_shr:1 neighbor shift, lane-local E128,
// exponent-only renorm every 16 steps via DPP-max + one readlane,
// wave-uniform rolling row byte-offset with clamp.

#define CTC_C 256

// full-wave shift-right-by-1, lane 0 gets 0 (DPP wave_shr:1, bound_ctrl:0)
__device__ __forceinline__ double wshr1_f64(double x) {
  int lo = __double2loint(x), hi = __double2hiint(x);
  lo = __builtin_amdgcn_update_dpp(0, lo, 0x138, 0xf, 0xf, true);
  hi = __builtin_amdgcn_update_dpp(0, hi, 0x138, 0xf, 0xf, true);
  return __hiloint2double(hi, lo);
}

template <int CTRL>
__device__ __forceinline__ unsigned dppmax(unsigned v) {
  unsigned t = (unsigned)__builtin_amdgcn_update_dpp(0, (int)v, CTRL, 0xf, 0xf, true);
  return v > t ? v : t;
}

// Wave-uniform power-of-2 renorm (exact). Positive doubles order by bit
// pattern; the max of the f64 high words carries the wave-max exponent.
// 4 DPP rounds (16-lane rows) + row_bcast15/31 + ONE readlane.
__device__ __forceinline__ void renorm(double& Oa, double& Ob, double& Ea,
                                       double& Eb, double& E128, double& logC) {
  unsigned m =       (unsigned)__double2hiint(Oa);
  unsigned h;
  h = (unsigned)__double2hiint(Ob);   m = m > h ? m : h;
  h = (unsigned)__double2hiint(Ea);   m = m > h ? m : h;
  h = (unsigned)__double2hiint(Eb);   m = m > h ? m : h;
  h = (unsigned)__double2hiint(E128); m = m > h ? m : h;
  m = dppmax<0xB1>(m);    // quad_perm [1,0,3,2]  (xor 1)
  m = dppmax<0x4E>(m);    // quad_perm [2,3,0,1]  (xor 2)
  m = dppmax<0x141>(m);   // row_half_mirror      (4<->4)
  m = dppmax<0x140>(m);   // row_mirror           (8<->8): row max everywhere
  m = dppmax<0x142>(m);   // row_bcast15
  m = dppmax<0x143>(m);   // row_bcast31: lane 63 holds the global max
  unsigned smax = (unsigned)__builtin_amdgcn_readlane((int)m, 63);
  int eb = (int)(smax >> 20);  // biased exponent of wave max (sign bit 0)
  // scale = 2^-(eb-1022) exactly; eb==0 (all zero) => 2^1022, still exact
  double s = __hiloint2double((int)((unsigned)(2045 - eb) << 20), 0);
  Oa *= s; Ob *= s; Ea *= s; Eb *= s; E128 *= s;
  logC += (double)(eb - 1022) * 0.6931471805599453;
}

__global__ __launch_bounds__(64)
void ctc_fwd(const float* __restrict__ lp, const int* __restrict__ y,
             const int* __restrict__ ilen, const int* __restrict__ tlen,
             float* __restrict__ out, int T, int B, int S) {
  const int l = threadIdx.x;            // 0..63
  const unsigned ROWB = (unsigned)(B * CTC_C * 4);   // bytes between rows

  int n[2], tl2[2];
  int fA[2], fB[2], fQ[2];              // per-lane float index in a row block
  bool skA[2], skB[2];
  double Oa[2], Ob[2], Ea[2], Eb[2], E128[2], logC[2];
  float cA[2], cB[2], cQ[2];            // carried: gathered values of row t

#pragma unroll
  for (int j = 0; j < 2; ++j) {
    const int b = 2 * (int)blockIdx.x + j;
    n[j]   = ilen[b] - 1;               // steps t = 1..n[j] (>= 767)
    tl2[j] = tlen[b];
    const int ya = y[(size_t)b * S + 2 * l];
    const int yb = y[(size_t)b * S + 2 * l + 1];
    const int yprev = __shfl_up(yb, 1); // y[2l-1] (garbage on lane 0, masked)
    skA[j] = (l > 0) && (ya != yprev);
    skB[j] = (yb != ya);
    fA[j] = b * CTC_C + ya;
    fB[j] = b * CTC_C + yb;
    fQ[j] = b * CTC_C;
    // init (t=0)
    const float* row0 = lp + (size_t)b * CTC_C;
    const int y0 = y[(size_t)b * S];
    Ea[j] = (l == 0) ? (double)__expf(row0[0])  : 0.;
    Oa[j] = (l == 0) ? (double)__expf(row0[y0]) : 0.;
    Eb[j] = 0.; Ob[j] = 0.; E128[j] = 0.; logC[j] = 0.;
    // prime carried regs with row 1
    const float* r1 = lp + (size_t)B * CTC_C;
    cA[j] = r1[fA[j]]; cB[j] = r1[fB[j]]; cQ[j] = r1[fQ[j]];
  }

  // wave-uniform rolling byte offset of the NEXT row (row t+1), clamped to
  // T-1; clamped over-reads near the end are never consumed
  const unsigned capR = (unsigned)(T - 1) * ROWB;
  unsigned uoff = 2u * ROWB;            // at step t=1 the next row is 2

  // One step for both batches. act literal-true in the main loop (guard
  // folds away); wave-uniform runtime bool in the tail (freeze commit).
#define CTC_STEP(act0_, act1_)                                              \
  do {                                                                      \
    double pa[2], pb[2], pq[2];                                             \
    _Pragma("unroll")                                                       \
    for (int j = 0; j < 2; ++j) {                                           \
      pa[j] = (double)__expf(cA[j]);                                        \
      pb[j] = (double)__expf(cB[j]);                                        \
      pq[j] = (double)__expf(cQ[j]);                                        \
    }                                                                       \
    {                                                                       \
      const float* rp = (const float*)((const char*)lp + uoff);             \
      _Pragma("unroll")                                                     \
      for (int j = 0; j < 2; ++j) {                                         \
        cA[j] = rp[fA[j]];                                                  \
        cB[j] = rp[fB[j]];                                                  \
        cQ[j] = rp[fQ[j]];                                                  \
      }                                                                     \
      unsigned un = uoff + ROWB;                                            \
      uoff = un < capR ? un : capR;                                         \
    }                                                                       \
    _Pragma("unroll")                                                       \
    for (int j = 0; j < 2; ++j) {                                           \
      const double Opm1 = wshr1_f64(Ob[j]);   /* O[2l-1], 0 on lane 0 */    \
      const double EaOp = Ea[j] + Opm1;                                     \
      const double EbOa = Eb[j] + Oa[j];                                    \
      const double tA = skA[j] ? EaOp : Ea[j];                              \
      const double tB = skB[j] ? EbOa : Eb[j];                              \
      const double nOa = (Oa[j] + tA) * pa[j];                              \
      const double nOb = (Ob[j] + tB) * pb[j];                              \
      const double nEa = EaOp * pq[j];                                      \
      const double nEb = EbOa * pq[j];                                      \
      const double nE  = (E128[j] + Ob[j]) * pq[j]; /* real on lane 63 */   \
      const bool act = (j == 0) ? (act0_) : (act1_);                        \
      if (act) {                                                            \
        Oa[j] = nOa; Ob[j] = nOb; Ea[j] = nEa; Eb[j] = nEb; E128[j] = nE;   \
      }                                                                     \
    }                                                                       \
  } while (0)

  const int nmin = n[0] < n[1] ? n[0] : n[1];
  const int nmax = n[0] > n[1] ? n[0] : n[1];
  const int ncomm = nmin >> 4;          // full 16-step chunks, both active

  for (int c = 0; c < ncomm; ++c) {
#pragma unroll
    for (int i = 0; i < 16; ++i) {
      CTC_STEP(true, true);
      if (i == 15) {
        renorm(Oa[0], Ob[0], Ea[0], Eb[0], E128[0], logC[0]);
        renorm(Oa[1], Ob[1], Ea[1], Eb[1], E128[1], logC[1]);
      }
    }
  }
  // tail: steps 16*ncomm+1 .. nmax with per-batch freeze (wave-uniform)
  for (int t = 16 * ncomm + 1; t <= nmax; ++t) {
    CTC_STEP(t <= n[0], t <= n[1]);
    if ((t & 15) == 0) {                // keep the 16-step renorm cadence
      renorm(Oa[0], Ob[0], Ea[0], Eb[0], E128[0], logC[0]);
      renorm(Oa[1], Ob[1], Ea[1], Eb[1], E128[1], logC[1]);
    }
  }
#undef CTC_STEP

  // Final per batch: ll = logC + log(alpha_exp[2*tl] + alpha_exp[2*tl-1])
  float acc = 0.f;
#pragma unroll
  for (int j = 0; j < 2; ++j) {
    const int tl = tl2[j];
    double vEa = __shfl(Ea[j], (tl >> 1) & 63);
    double vEb = __shfl(Eb[j], (tl >> 1) & 63);
    double vE128 = __shfl(E128[j], 63); // the one real E[128]
    double vhi = (tl == S) ? vE128 : ((tl & 1) ? vEb : vEa);
    const int s2 = tl - 1;
    double vOa = __shfl(Oa[j], (s2 >> 1) & 63);
    double vOb = __shfl(Ob[j], (s2 >> 1) & 63);
    double vlo = (s2 & 1) ? vOb : vOa;

    double sum = vhi + vlo;
    double loss;
    if (sum > 0.) {
      loss = -(logC[j] + log(sum));
    } else {
      loss = 1e30;                      // -inf likelihood
    }
    if (!(loss < 5.0e8)) loss = 0.;     // zero_infinity (catches inf/NaN)
    acc += (float)(loss / (double)tl / (double)B);
  }
  if (l == 0) atomicAdd(out, acc);
}

extern "C" void kernel_launch(void* const* d_in, const int* in_sizes, int n_in,
                              void* d_out, int out_size, void* d_ws, size_t ws_size,
                              hipStream_t stream) {
  const float* lp   = (const float*)d_in[0];
  const int*   yy   = (const int*)d_in[1];
  const int*   ilen = (const int*)d_in[2];
  const int*   tlen = (const int*)d_in[3];
  float* out = (float*)d_out;

  int B = in_sizes[2];
  int S = in_sizes[1] / B;
  int T = in_sizes[0] / (B * CTC_C);

  hipMemsetAsync(out, 0, sizeof(float), stream);
  ctc_fwd<<<B / 2, 64, 0, stream>>>(lp, yy, ilen, tlen, out, T, B, S);
}

// Round 9
// 254.087 us; speedup vs baseline: 1.9384x; 1.9384x over previous
//
#include <hip/hip_runtime.h>

// CTC loss forward, T=1024, B=128, C=256, S=128, L=2S+1=257.
// One wave (64 lanes) per batch. Lane l owns odd states O[2l],O[2l+1]
// (labels y[2l],y[2l+1]) and blank states E[2l],E[2l+1]; E[128] kept
// LANE-LOCAL (only lane 63's copy is real; broadcast once at the end).
// Exp-domain recursion in FP64 with exact power-of-2 renorm every 16 steps.
//
// R9 = R3's verified structure + __launch_bounds__(64, 1).
// Post-mortem R1-R8: every pipelining attempt collapsed to "loads sunk to
// uses, minimal VGPRs" (VGPR_Count 48/72/60/48 across rounds; R8 even
// SEQUENCED its two batches, paying two exposed round-trips -> 3x worse).
// The consistent mechanism: the scheduler's register-pressure target
// defaults to multi-wave occupancy, so it sinks/clusters loads to shrink
// liveness. This kernel runs ONE wave per CU (128 blocks / 256 CUs); the
// never-tried fix is min-waves-per-EU = 1, which hands the scheduler the
// whole register file and disarms the pressure heuristic. Single-token
// discriminating test: VGPR_Count >= ~110 means the 16-deep pipeline is
// finally live (expect big win); VGPR_Count <= 72 kills the theory (pivot
// to LDS chunk-amortized staging next).
//
// Kept (verified absmax 0.0): 16-deep prefetch arrays, per-step
// sched_barrier(0) (R3: -24cy/step), wave-uniform rolling row offset,
// DPP wave_shr:1 shift, lane-local E128, exponent-only renorm (R6 variant:
// DPP-max + row_bcast15/31 + ONE readlane), 16-step renorm cadence.

#define CTC_C 256
#define DEP 16    // prefetch depth in steps; 3*DEP = 48 loads in flight

// full-wave shift-right-by-1, lane 0 gets 0 (DPP wave_shr:1, bound_ctrl:0)
__device__ __forceinline__ double wshr1_f64(double x) {
  int lo = __double2loint(x), hi = __double2hiint(x);
  lo = __builtin_amdgcn_update_dpp(0, lo, 0x138, 0xf, 0xf, true);
  hi = __builtin_amdgcn_update_dpp(0, hi, 0x138, 0xf, 0xf, true);
  return __hiloint2double(hi, lo);
}

template <int CTRL>
__device__ __forceinline__ unsigned dppmax(unsigned v) {
  unsigned t = (unsigned)__builtin_amdgcn_update_dpp(0, (int)v, CTRL, 0xf, 0xf, true);
  return v > t ? v : t;
}

// Wave-uniform power-of-2 renorm (exact). Positive doubles order by bit
// pattern; the max of the f64 high words carries the wave-max exponent.
// 4 DPP rounds (16-lane rows) + row_bcast15/31 + ONE readlane.
__device__ __forceinline__ void renorm(double& Oa, double& Ob, double& Ea,
                                       double& Eb, double& E128, double& logC) {
  unsigned m =       (unsigned)__double2hiint(Oa);
  unsigned h;
  h = (unsigned)__double2hiint(Ob);   m = m > h ? m : h;
  h = (unsigned)__double2hiint(Ea);   m = m > h ? m : h;
  h = (unsigned)__double2hiint(Eb);   m = m > h ? m : h;
  h = (unsigned)__double2hiint(E128); m = m > h ? m : h;
  m = dppmax<0xB1>(m);    // quad_perm [1,0,3,2]  (xor 1)
  m = dppmax<0x4E>(m);    // quad_perm [2,3,0,1]  (xor 2)
  m = dppmax<0x141>(m);   // row_half_mirror      (4<->4)
  m = dppmax<0x140>(m);   // row_mirror           (8<->8): row max everywhere
  m = dppmax<0x142>(m);   // row_bcast15
  m = dppmax<0x143>(m);   // row_bcast31: lane 63 holds the global max
  unsigned smax = (unsigned)__builtin_amdgcn_readlane((int)m, 63);
  int eb = (int)(smax >> 20);  // biased exponent of wave max (sign bit 0)
  // scale = 2^-(eb-1022) exactly; eb==0 (all zero) => 2^1022, still exact
  double s = __hiloint2double((int)((unsigned)(2045 - eb) << 20), 0);
  Oa *= s; Ob *= s; Ea *= s; Eb *= s; E128 *= s;
  logC += (double)(eb - 1022) * 0.6931471805599453;
}

__global__ __launch_bounds__(64, 1)   // <-- THE change: 1 wave/EU target
void ctc_fwd(const float* __restrict__ lp, const int* __restrict__ y,
             const int* __restrict__ ilen, const int* __restrict__ tlen,
             float* __restrict__ out, int T, int B, int S) {
  const int l = threadIdx.x;            // 0..63
  const int b = blockIdx.x;
  const size_t rowstrideF = (size_t)B * CTC_C;       // floats between rows
  const unsigned ROWB = (unsigned)(B * CTC_C * 4);   // bytes between rows

  const int len = ilen[b];              // input length, steps t=1..len-1
  const int tl  = tlen[b];              // target length

  const int ya = y[(size_t)b * S + 2 * l];
  const int yb = y[(size_t)b * S + 2 * l + 1];
  const int yprev = __shfl_up(yb, 1);   // y[2l-1] (garbage on lane 0, masked)
  const bool skipA = (l > 0) && (ya != yprev);
  const bool skipB = (yb != ya);

  // Init (t=0)
  const float* row0 = lp + (size_t)b * CTC_C;
  const int y0 = y[(size_t)b * S];
  double Ea = (l == 0) ? (double)__expf(row0[0])  : 0.;
  double Oa = (l == 0) ? (double)__expf(row0[y0]) : 0.;
  double Eb = 0., Ob = 0., E128 = 0., logC = 0.;

  // Loop-invariant per-lane element indices within a row block
  const int fA = b * CTC_C + ya;        // gathered label A
  const int fB = b * CTC_C + yb;        // gathered label B
  const int fQ = b * CTC_C;             // blank

  // ---- prime the pipeline: rows 1..DEP, slot = t & 15 ----
  float rA[DEP], rB[DEP], rQ[DEP];
#pragma unroll
  for (int t = 1; t <= DEP; ++t) {
    const float* r = lp + (size_t)t * rowstrideF;
    rA[t & 15] = r[fA]; rB[t & 15] = r[fB]; rQ[t & 15] = r[fQ];
  }

  // Rolling WAVE-UNIFORM byte offset of the refill row (row t+DEP, clamped
  // to T-1; over-reads of the last row are never consumed). Scalar math.
  const unsigned capR = (unsigned)(T - 1) * ROWB;
  unsigned uoff = (unsigned)(DEP + 1) * ROWB;   // refill row for step t=1

  // One recursion step. Chunks start at t ≡ 1 (mod 16) so slots are
  // compile-time. sched_barrier(0) at each step boundary stops the machine
  // scheduler from clustering refill loads across steps.
#define CTC_STEP(i_)                                                          \
  do {                                                                        \
    const int d = (1 + (i_)) & 15;                                            \
    const double pa = (double)__expf(rA[d]);                                  \
    const double pb = (double)__expf(rB[d]);                                  \
    const double pq = (double)__expf(rQ[d]);                                  \
    {                                                                         \
      const float* rp = (const float*)((const char*)lp + uoff);               \
      rA[d] = rp[fA]; rB[d] = rp[fB]; rQ[d] = rp[fQ];                         \
      unsigned un = uoff + ROWB;                                              \
      uoff = un < capR ? un : capR;                                           \
    }                                                                         \
    const double Opm1 = wshr1_f64(Ob);      /* O[2l-1], 0 on lane 0 */        \
    const double EaOp = Ea + Opm1;                                            \
    const double EbOa = Eb + Oa;                                              \
    const double tA = skipA ? EaOp : Ea;                                      \
    const double tB = skipB ? EbOa : Eb;                                      \
    const double nOa = (Oa + tA) * pa;                                        \
    const double nOb = (Ob + tB) * pb;                                        \
    Ea = EaOp * pq;                                                           \
    Eb = EbOa * pq;                                                           \
    E128 = (E128 + Ob) * pq;                /* real only on lane 63 */        \
    Oa = nOa; Ob = nOb;                                                       \
    __builtin_amdgcn_sched_barrier(0);                                        \
  } while (0)

  const int nsteps = len - 1;           // steps t = 1..nsteps (len >= 768)
  const int nch = nsteps >> 4;          // full 16-step chunks
  const int rem = nsteps & 15;

  for (int c = 0; c < nch; ++c) {
#pragma unroll
    for (int i = 0; i < 16; ++i) {
      CTC_STEP(i);
      if (i == 15) renorm(Oa, Ob, Ea, Eb, E128, logC);
    }
  }
  if (rem) {                            // guarded tail chunk (wave-uniform)
#pragma unroll
    for (int i = 0; i < 16; ++i) {
      if (i < rem) CTC_STEP(i);         // <=15 extra steps: f64 margin ok
    }
  }
#undef CTC_STEP

  // Final: ll = logC + log(alpha_exp[2*tl] + alpha_exp[2*tl-1])
  double vEa = __shfl(Ea, (tl >> 1) & 63);
  double vEb = __shfl(Eb, (tl >> 1) & 63);
  double vE128 = __shfl(E128, 63);      // the one real E[128]
  double vhi = (tl == S) ? vE128 : ((tl & 1) ? vEb : vEa);
  const int s2 = tl - 1;
  double vOa = __shfl(Oa, (s2 >> 1) & 63);
  double vOb = __shfl(Ob, (s2 >> 1) & 63);
  double vlo = (s2 & 1) ? vOb : vOa;

  double sum = vhi + vlo;
  double loss;
  if (sum > 0.) {
    loss = -(logC + log(sum));
  } else {
    loss = 1e30;                        // -inf likelihood
  }
  if (!(loss < 5.0e8)) loss = 0.;       // zero_infinity (catches inf/NaN)
  float contrib = (float)(loss / (double)tl / (double)B);
  if (l == 0) atomicAdd(out, contrib);
}

extern "C" void kernel_launch(void* const* d_in, const int* in_sizes, int n_in,
                              void* d_out, int out_size, void* d_ws, size_t ws_size,
                              hipStream_t stream) {
  const float* lp   = (const float*)d_in[0];
  const int*   yy   = (const int*)d_in[1];
  const int*   ilen = (const int*)d_in[2];
  const int*   tlen = (const int*)d_in[3];
  float* out = (float*)d_out;

  int B = in_sizes[2];
  int S = in_sizes[1] / B;
  int T = in_sizes[0] / (B * CTC_C);

  hipMemsetAsync(out, 0, sizeof(float), stream);
  ctc_fwd<<<B, 64, 0, stream>>>(lp, yy, ilen, tlen, out, T, B, S);
}

// Round 10
// 248.932 us; speedup vs baseline: 1.9786x; 1.0207x over previous
//
#include <hip/hip_runtime.h>

// CTC loss forward, T=1024, B=128, C=256, S=128, L=2S+1=257.
// R10: DIAGNOSTIC ROUND. Real blocks (0..B-1) are byte-identical to R6
// (best verified: 114.4us, absmax 0.0). Blocks B..2B-1 run on the 128
// OTHERWISE-IDLE CUs: the same step body with NO memory access (opaque
// register-fed probabilities) for 2048 steps. Dispatch = max(real, shadow):
//   ~115us  -> compute-sans-loads <135cy/step -> stall is the load path
//   ~190-240us -> recursion+exp itself is ~230-280cy/step -> compute-bound
// R1-R9 post-mortem: every load arrangement (collapsed/live/atomic/LDS-DMA,
// VGPR 44..72) = 114-135us, warm-L3 == cold, renorm halving null, and R4's
// genuinely-pinned atomic pipeline was NOT faster => "exposed load latency"
// is falsified as a family; remaining split (compute vs interface) is not
// resolvable from derived counters. This round buys the answer with idle HW.

#define CTC_C 256
#define RING 16    // LDS ring depth (rows); GLL lead = 16 steps

typedef unsigned int u32;

// one coalesced row-stage: lane i pulls 16B at g+16i into lds_base+16i
__device__ __forceinline__ void gll16(const void* g, void* l) {
  __builtin_amdgcn_global_load_lds(
      (const __attribute__((address_space(1))) u32*)g,
      (__attribute__((address_space(3))) u32*)l, 16, 0, 0);
}

// full-wave shift-right-by-1, lane 0 gets 0 (DPP wave_shr:1, bound_ctrl:0)
__device__ __forceinline__ double wshr1_f64(double x) {
  int lo = __double2loint(x), hi = __double2hiint(x);
  lo = __builtin_amdgcn_update_dpp(0, lo, 0x138, 0xf, 0xf, true);
  hi = __builtin_amdgcn_update_dpp(0, hi, 0x138, 0xf, 0xf, true);
  return __hiloint2double(hi, lo);
}

template <int CTRL>
__device__ __forceinline__ unsigned dppmax(unsigned v) {
  unsigned t = (unsigned)__builtin_amdgcn_update_dpp(0, (int)v, CTRL, 0xf, 0xf, true);
  return v > t ? v : t;
}

// Wave-uniform power-of-2 renorm (exact). Positive doubles order by bit
// pattern; max of the f64 high words carries the wave-max exponent.
// 4 DPP rounds + row_bcast15/31 + ONE readlane.
__device__ __forceinline__ void renorm(double& Oa, double& Ob, double& Ea,
                                       double& Eb, double& E128, double& logC) {
  unsigned m =       (unsigned)__double2hiint(Oa);
  unsigned h;
  h = (unsigned)__double2hiint(Ob);   m = m > h ? m : h;
  h = (unsigned)__double2hiint(Ea);   m = m > h ? m : h;
  h = (unsigned)__double2hiint(Eb);   m = m > h ? m : h;
  h = (unsigned)__double2hiint(E128); m = m > h ? m : h;
  m = dppmax<0xB1>(m);    // quad_perm [1,0,3,2]  (xor 1)
  m = dppmax<0x4E>(m);    // quad_perm [2,3,0,1]  (xor 2)
  m = dppmax<0x141>(m);   // row_half_mirror      (4<->4)
  m = dppmax<0x140>(m);   // row_mirror           (8<->8): row max everywhere
  m = dppmax<0x142>(m);   // row_bcast15
  m = dppmax<0x143>(m);   // row_bcast31: lane 63 holds the global max
  unsigned smax = (unsigned)__builtin_amdgcn_readlane((int)m, 63);
  int eb = (int)(smax >> 20);  // biased exponent of wave max (sign bit 0)
  double s = __hiloint2double((int)((unsigned)(2045 - eb) << 20), 0);
  Oa *= s; Ob *= s; Ea *= s; Eb *= s; E128 *= s;
  logC += (double)(eb - 1022) * 0.6931471805599453;
}

__global__ __launch_bounds__(64)
void ctc_fwd(const float* __restrict__ lp, const int* __restrict__ y,
             const int* __restrict__ ilen, const int* __restrict__ tlen,
             float* __restrict__ out, int T, int B, int S) {
  __shared__ __align__(16) float ring[RING][CTC_C];   // 16KB row ring

  const int l = threadIdx.x;            // 0..63

  if ((int)blockIdx.x >= B) {
    // ---------------- SHADOW diagnostic block (no memory in loop) --------
    const int b2 = (int)blockIdx.x - B;
    const float* row0s = lp + (size_t)b2 * CTC_C;
    float sa = row0s[l];                    // log-softmax vals, ~[-15, 0]
    float sb = row0s[(l * 7 + 13) & 255];
    float sq = row0s[128];
    const bool skA = (l > 0), skB = ((l & 3) != 1);
    double Oa = (l == 0) ? 1.0 : 0.;
    double Ob = 0., Ea = (l == 0) ? 0.5 : 0., Eb = 0., E128 = 0., logC = 0.;
    for (int c = 0; c < 128; ++c) {         // 128*16 = 2048 steps
#pragma unroll
      for (int i = 0; i < 16; ++i) {
        asm volatile("" : "+v"(sa), "+v"(sb), "+v"(sq));  // defeat hoisting
        const double pa = (double)__expf(sa);
        const double pb = (double)__expf(sb);
        const double pq = (double)__expf(sq);
        const double Opm1 = wshr1_f64(Ob);
        const double EaOp = Ea + Opm1;
        const double EbOa = Eb + Oa;
        const double tA = skA ? EaOp : Ea;
        const double tB = skB ? EbOa : Eb;
        const double nOa = (Oa + tA) * pa;
        const double nOb = (Ob + tB) * pb;
        Ea = EaOp * pq;
        Eb = EbOa * pq;
        E128 = (E128 + Ob) * pq;
        Oa = nOa; Ob = nOb;
        if (i == 15) renorm(Oa, Ob, Ea, Eb, E128, logC);
      }
    }
    asm volatile("" :: "v"(Oa), "v"(Ob), "v"(Ea), "v"(Eb), "v"(E128), "v"(logC));
    return;
  }

  // ---------------- REAL path: byte-identical to R6 ----------------------
  const int b = blockIdx.x;
  const unsigned ROWB = (unsigned)(B * CTC_C * 4);   // bytes between rows

  const int len = ilen[b];              // input length, steps t=1..len-1
  const int tl  = tlen[b];              // target length

  const int ya = y[(size_t)b * S + 2 * l];
  const int yb = y[(size_t)b * S + 2 * l + 1];
  const int yprev = __shfl_up(yb, 1);   // y[2l-1] (garbage on lane 0, masked)
  const bool skipA = (l > 0) && (ya != yprev);
  const bool skipB = (yb != ya);

  // Init (t=0)
  const float* row0 = lp + (size_t)b * CTC_C;
  const int y0 = y[(size_t)b * S];
  double Ea = (l == 0) ? (double)__expf(row0[0])  : 0.;
  double Oa = (l == 0) ? (double)__expf(row0[y0]) : 0.;
  double Eb = 0., Ob = 0., E128 = 0., logC = 0.;

  // per-lane global byte pointer: lane i owns bytes 16i..16i+15 of b's row
  const char* gLane = (const char*)lp + (size_t)b * CTC_C * 4 + 16 * (size_t)l;

  // drain prologue VMEM so vmcnt counts only our row-stages
  asm volatile("s_waitcnt vmcnt(0)" ::: "memory");
  __builtin_amdgcn_sched_barrier(0);

  // prime the LDS ring with rows 1..16 (len >= 768, always valid)
#pragma unroll
  for (int t = 1; t <= RING; ++t)
    gll16(gLane + (size_t)t * ROWB, &ring[t & 15][0]);
  asm volatile("s_waitcnt vmcnt(0)" ::: "memory");
  __builtin_amdgcn_sched_barrier(0);

  // pf ring (4 deep): rows 1..4 in slots 1,2,3,0  (slot = row & 3)
  float pfA[4], pfB[4], pfQ[4];
#pragma unroll
  for (int t = 1; t <= 4; ++t) {
    pfA[t & 3] = ring[t & 15][ya];
    pfB[t & 3] = ring[t & 15][yb];
    pfQ[t & 3] = ring[t & 15][0];
  }
  // e ring (2 deep): exp'd probabilities, slot = row & 1. Prime row 1.
  double eA2[2], eB2[2], eQ2[2];
  eA2[1] = (double)__expf(pfA[1]);
  eB2[1] = (double)__expf(pfB[1]);
  eQ2[1] = (double)__expf(pfQ[1]);

  const unsigned capR = (unsigned)(T - 1) * ROWB;
  unsigned uoff = (unsigned)(RING + 1) * ROWB;     // stage row for step t=1

#define CTC_STEP(i_)                                                          \
  do {                                                                        \
    const int eu = (1 + (i_)) & 1;          /* e slot for row t        */     \
    const int en = (2 + (i_)) & 1;          /* e slot for row t+1      */     \
    const int pn = (2 + (i_)) & 3;          /* pf slot of row t+1      */     \
    const int pr = (5 + (i_)) & 3;          /* pf slot for row t+4     */     \
    const int sl = (5 + (i_)) & 15;         /* LDS slot of row t+4     */     \
    const int sg = (1 + (i_)) & 15;         /* LDS slot for row t+16   */     \
    const double pa = eA2[eu], pb = eB2[eu], pq = eQ2[eu];                    \
    eA2[en] = (double)__expf(pfA[pn]);                                        \
    eB2[en] = (double)__expf(pfB[pn]);                                        \
    eQ2[en] = (double)__expf(pfQ[pn]);                                        \
    gll16(gLane + uoff, &ring[sg][0]);                                        \
    {                                                                         \
      unsigned un = uoff + ROWB;                                              \
      uoff = un < capR ? un : capR;                                           \
    }                                                                         \
    asm volatile("s_waitcnt vmcnt(12)" ::: "memory");                         \
    __builtin_amdgcn_sched_barrier(0);                                        \
    pfA[pr] = ring[sl][ya];                                                   \
    pfB[pr] = ring[sl][yb];                                                   \
    pfQ[pr] = ring[sl][0];                                                    \
    const double Opm1 = wshr1_f64(Ob);      /* O[2l-1], 0 on lane 0 */        \
    const double EaOp = Ea + Opm1;                                            \
    const double EbOa = Eb + Oa;                                              \
    const double tA = skipA ? EaOp : Ea;                                      \
    const double tB = skipB ? EbOa : Eb;                                      \
    const double nOa = (Oa + tA) * pa;                                        \
    const double nOb = (Ob + tB) * pb;                                        \
    Ea = EaOp * pq;                                                           \
    Eb = EbOa * pq;                                                           \
    E128 = (E128 + Ob) * pq;                /* real only on lane 63 */        \
    Oa = nOa; Ob = nOb;                                                       \
  } while (0)

  const int nsteps = len - 1;           // steps t = 1..nsteps (len >= 768)
  const int nch = nsteps >> 4;          // full 16-step chunks
  const int rem = nsteps & 15;

  for (int c = 0; c < nch; ++c) {
#pragma unroll
    for (int i = 0; i < 16; ++i) {
      CTC_STEP(i);
      if (i == 15) renorm(Oa, Ob, Ea, Eb, E128, logC);
    }
  }
  if (rem) {                            // guarded tail chunk (wave-uniform)
#pragma unroll
    for (int i = 0; i < 16; ++i) {
      if (i < rem) CTC_STEP(i);         // <=15 extra steps: f64 margin ok
    }
  }
#undef CTC_STEP

  // Final: ll = logC + log(alpha_exp[2*tl] + alpha_exp[2*tl-1])
  double vEa = __shfl(Ea, (tl >> 1) & 63);
  double vEb = __shfl(Eb, (tl >> 1) & 63);
  double vE128 = __shfl(E128, 63);      // the one real E[128]
  double vhi = (tl == S) ? vE128 : ((tl & 1) ? vEb : vEa);
  const int s2 = tl - 1;
  double vOa = __shfl(Oa, (s2 >> 1) & 63);
  double vOb = __shfl(Ob, (s2 >> 1) & 63);
  double vlo = (s2 & 1) ? vOb : vOa;

  double sum = vhi + vlo;
  double loss;
  if (sum > 0.) {
    loss = -(logC + log(sum));
  } else {
    loss = 1e30;                        // -inf likelihood
  }
  if (!(loss < 5.0e8)) loss = 0.;       // zero_infinity (catches inf/NaN)
  float contrib = (float)(loss / (double)tl / (double)B);
  if (l == 0) atomicAdd(out, contrib);
}

extern "C" void kernel_launch(void* const* d_in, const int* in_sizes, int n_in,
                              void* d_out, int out_size, void* d_ws, size_t ws_size,
                              hipStream_t stream) {
  const float* lp   = (const float*)d_in[0];
  const int*   yy   = (const int*)d_in[1];
  const int*   ilen = (const int*)d_in[2];
  const int*   tlen = (const int*)d_in[3];
  float* out = (float*)d_out;

  int B = in_sizes[2];
  int S = in_sizes[1] / B;
  int T = in_sizes[0] / (B * CTC_C);

  hipMemsetAsync(out, 0, sizeof(float), stream);
  ctc_fwd<<<2 * B, 64, 0, stream>>>(lp, yy, ilen, tlen, out, T, B, S);
}